// Round 1
// 344.275 us; speedup vs baseline: 1.0020x; 1.0020x over previous
//
#include <hip/hip_runtime.h>

// CombineEmbedder R5: fp8(e4m3) fragment-permuted gather mirror of x (halves random
// gather bytes, 1 cache line/row), own-row residual prefetched to registers at
// kernel entry, occupancy bumps (prop: 5 waves/EU cap; phase_a: bf16-packed hv).
// N=262144, FEAT=64, D=128, DEPTH=2.
//
// ws layout (bytes):
//   [0,      16384)  wembF  bf16 frags  (t*2+s)*64+lane (norm folded)
//   [16384,  49152)  wlF    bf16 frags  (t*4+s)*64+lane
//   [49152,  81920)  wnF    bf16 frags  (0.5 gather-mean folded)
//   [81920,  82432)  bembP  fp32[128]
//   [1 MB,   65 MB)  x1     bf16 [N][128] ping buffer
//   [65 MB,  97 MB)  x0f8   fp8  [N][128] permuted gather mirror of x0
//   [97 MB, 129 MB)  x1f8   fp8  [N][128] permuted gather mirror of x1
// x0 (bf16) aliases d_out's x_main region (dead before final fp32 write).
//
// fp8 permuted row layout: pos = (k>>5)*8 + ((k>>3)&3)*32 + (k&7)
//   -> lane q's A-fragment s2 is 8 contiguous bytes at q*32 + s2*8.

#define NROWS 262144
#define NBLK  4096

typedef __attribute__((ext_vector_type(8))) short bhalf8;
typedef __attribute__((ext_vector_type(4))) float f32x4;
typedef __attribute__((ext_vector_type(2))) float f32x2;
typedef __attribute__((ext_vector_type(4))) unsigned int u32x4;
typedef __attribute__((ext_vector_type(2))) unsigned int u32x2;

__device__ __forceinline__ unsigned short f2bf(float x) {
    union { float f; unsigned u; } v; v.f = x;
    unsigned r = v.u + 0x7FFFu + ((v.u >> 16) & 1u);   // RNE
    return (unsigned short)(r >> 16);
}
__device__ __forceinline__ float bflo(unsigned u) {
    union { unsigned u; float f; } v; v.u = u << 16; return v.f;
}
__device__ __forceinline__ float bfhi(unsigned u) {
    union { unsigned u; float f; } v; v.u = u & 0xFFFF0000u; return v.f;
}
__device__ __forceinline__ float leaky(float x) { return x >= 0.0f ? x : 0.01f * x; }

__device__ __forceinline__ unsigned pk4fp8(float a, float b, float c, float d) {
    int r = __builtin_amdgcn_cvt_pk_fp8_f32(a, b, 0, false);
    r = __builtin_amdgcn_cvt_pk_fp8_f32(c, d, r, true);
    return (unsigned)r;
}

// ---------------- setup: pack weights to fragment-major bf16, fold norms ----------------
__global__ void __launch_bounds__(256)
setup_kernel(const float* __restrict__ smean, const float* __restrict__ sstd,
             const float* __restrict__ Wemb, const float* __restrict__ bemb,
             const float* __restrict__ Wl, const float* __restrict__ Wn,
             unsigned short* __restrict__ wpack, float* __restrict__ bembP)
{
    int task = blockIdx.x * 256 + threadIdx.x;
    if (blockIdx.x < 160) {
        if (task < 8192) {                       // wembF: frag=(t*2+s), K=64
            int f = task >> 9, idx = task & 511;
            int t = f >> 1, s = f & 1, lane = idx >> 3, j = idx & 7;
            int n = t * 16 + (lane & 15), k = s * 32 + (lane >> 4) * 8 + j;
            wpack[task] = f2bf(Wemb[k * 128 + n] / (sstd[k] + 0.001f));
        } else if (task < 24576) {               // wlF: frag=(t*4+s), K=128
            int u = task - 8192;
            int f = u >> 9, idx = u & 511;
            int t = f >> 2, s = f & 3, lane = idx >> 3, j = idx & 7;
            int n = t * 16 + (lane & 15), k = s * 32 + (lane >> 4) * 8 + j;
            wpack[task] = f2bf(Wl[k * 128 + n]);
        } else if (task < 40960) {               // wnF: 0.5 folded
            int u = task - 24576;
            int f = u >> 9, idx = u & 511;
            int t = f >> 2, s = f & 3, lane = idx >> 3, j = idx & 7;
            int n = t * 16 + (lane & 15), k = s * 32 + (lane >> 4) * 8 + j;
            wpack[task] = f2bf(0.5f * Wn[k * 128 + n]);
        }
    } else {                                     // bembP[n] = bemb[n] - sum_k mu_k/sig_k * Wemb[k][n]
        int n = threadIdx.x;
        if (n < 128) {
            float acc = bemb[n];
            for (int k = 0; k < 64; k++)
                acc -= smean[k] / (sstd[k] + 0.001f) * Wemb[k * 128 + n];
            bembP[n] = acc;
        }
    }
}

// ---------------- phase A: embed + residual layer + layernorm*0.5 ----------------
__global__ void __launch_bounds__(256, 4)
phase_a_kernel(const float* __restrict__ feats,
               const unsigned short* __restrict__ wembF,
               const float* __restrict__ bembP,
               const unsigned short* __restrict__ wlF,
               const float* __restrict__ bl,
               unsigned short* __restrict__ xout,
               unsigned char* __restrict__ xf8)
{
    __shared__ __align__(16) short hb[64 * 136];   // 17408 B
    const int tid = threadIdx.x, lane = tid & 63, wv = tid >> 6;
    const int m = lane & 15, q = lane >> 4;
    const int r0 = blockIdx.x * 64;

    const bhalf8* wbe = (const bhalf8*)wembF;
    const bhalf8* wbl = (const bhalf8*)wlF;

    // mm1 A-fragments straight from feats (norm folded into weights)
    bhalf8 af[2];
    #pragma unroll
    for (int s = 0; s < 2; s++) {
        const float* fp = feats + (size_t)(r0 + wv * 16 + m) * 64 + s * 32 + q * 8;
        f32x4 f0 = *(const f32x4*)fp;
        f32x4 f1 = *(const f32x4*)(fp + 4);
        bhalf8 a;
        #pragma unroll
        for (int jj = 0; jj < 4; jj++) { a[jj] = (short)f2bf(f0[jj]); a[4 + jj] = (short)f2bf(f1[jj]); }
        af[s] = a;
    }
    f32x4 acc[8] = {};
    #pragma unroll
    for (int s = 0; s < 2; s++)
        #pragma unroll
        for (int t = 0; t < 8; t++)
            acc[t] = __builtin_amdgcn_mfma_f32_16x16x32_bf16(af[s], wbe[(t * 2 + s) * 64 + lane], acc[t], 0, 0, 0);

    // h = leaky(acc + bembP): keep bf16-packed in regs for residual (saves 16 VGPRs),
    // bf16 to LDS for mm2-A
    unsigned hvp[8][2];
    #pragma unroll
    for (int t = 0; t < 8; t++) {
        float be = bembP[t * 16 + m];
        unsigned short hq[4];
        #pragma unroll
        for (int p = 0; p < 4; p++) {
            float h = leaky(acc[t][p] + be);
            hq[p] = f2bf(h);
            hb[(wv * 16 + q * 4 + p) * 136 + t * 16 + m] = (short)hq[p];
        }
        hvp[t][0] = (unsigned)hq[0] | ((unsigned)hq[1] << 16);
        hvp[t][1] = (unsigned)hq[2] | ((unsigned)hq[3] << 16);
    }
    // mm2: A from hb (own-tile, in-wave dep only), B from global frags
    f32x4 acc2[8] = {};
    #pragma unroll
    for (int s = 0; s < 4; s++) {
        bhalf8 a = *(const bhalf8*)&hb[(wv * 16 + m) * 136 + s * 32 + q * 8];
        #pragma unroll
        for (int t = 0; t < 8; t++)
            acc2[t] = __builtin_amdgcn_mfma_f32_16x16x32_bf16(a, wbl[(t * 4 + s) * 64 + lane], acc2[t], 0, 0, 0);
    }

    // t = leaky(leaky(acc2+bl)) + h ; layernorm ; *0.5
    float tv[8][4];
    float sum[4] = {0, 0, 0, 0}, ssq[4] = {0, 0, 0, 0};
    #pragma unroll
    for (int t = 0; t < 8; t++) {
        float bb = bl[t * 16 + m];
        float h0 = bflo(hvp[t][0]), h1 = bfhi(hvp[t][0]);
        float h2 = bflo(hvp[t][1]), h3 = bfhi(hvp[t][1]);
        float hvv[4] = { h0, h1, h2, h3 };
        #pragma unroll
        for (int p = 0; p < 4; p++) {
            float v = leaky(leaky(acc2[t][p] + bb)) + hvv[p];
            tv[t][p] = v;
            sum[p] += v; ssq[p] += v * v;
        }
    }
    #pragma unroll
    for (int p = 0; p < 4; p++) {
        #pragma unroll
        for (int d = 1; d < 16; d <<= 1) {
            sum[p] += __shfl_xor(sum[p], d, 64);
            ssq[p] += __shfl_xor(ssq[p], d, 64);
        }
    }
    #pragma unroll
    for (int p = 0; p < 4; p++) {
        float mu  = sum[p] * (1.0f / 128.0f);
        float var = ssq[p] * (1.0f / 128.0f) - mu * mu;
        float rs  = rsqrtf(var + 1e-5f) * 0.5f;
        int row = wv * 16 + q * 4 + p;
        #pragma unroll
        for (int t = 0; t < 8; t++)
            hb[row * 136 + t * 16 + m] = (short)f2bf((tv[t][p] - mu) * rs);   // own-tile overwrite, safe
    }
    __syncthreads();
    for (int c = tid; c < 64 * 16; c += 256) {
        int row = c >> 4, cb = c & 15;
        u32x4 hv4 = *reinterpret_cast<const u32x4*>(&hb[row * 136 + cb * 8]);
        *reinterpret_cast<u32x4*>(&xout[(size_t)(r0 + row) * 128 + cb * 8]) = hv4;
        // fp8 gather mirror (permuted fragment layout)
        u32x2 pf;
        pf[0] = pk4fp8(bflo(hv4[0]), bfhi(hv4[0]), bflo(hv4[1]), bfhi(hv4[1]));
        pf[1] = pk4fp8(bflo(hv4[2]), bfhi(hv4[2]), bflo(hv4[3]), bfhi(hv4[3]));
        *reinterpret_cast<u32x2*>(xf8 + (size_t)(r0 + row) * 128 + (cb & 3) * 32 + (cb >> 2) * 8) = pf;
    }
}

// ---------------- prop: fp8 gather(+) -> node matmul -> rezero residual (+heads) ----------------
template <typename TOUT>
__global__ void __launch_bounds__(256, 5)
prop_kernel(const unsigned short* __restrict__ xin,      // bf16 (residual, exact path)
            const unsigned char* __restrict__ xf8,       // fp8 permuted (gather path)
            const int* __restrict__ idmap,
            const unsigned short* __restrict__ wnF, const float* __restrict__ bn,
            const float* __restrict__ rez, const float* __restrict__ Ww,
            const float* __restrict__ Wv, TOUT* __restrict__ xout,
            unsigned char* __restrict__ xf8out,
            float* __restrict__ wout, float* __restrict__ vout, int final_pass)
{
    __shared__ __align__(16) short gls[64 * 136];
    const int tid = threadIdx.x, lane = tid & 63, wv = tid >> 6;
    const int m = lane & 15, q = lane >> 4;
    const int r0 = blockIdx.x * 64;
    const bhalf8* wbn = (const bhalf8*)wnF;

    // prefetch own rows for residual: coalesced 1KB/wave, issued before anything else
    const int crow = tid >> 4, ccb = tid & 15;
    u32x4 xown[4];
    #pragma unroll
    for (int i = 0; i < 4; i++)
        xown[i] = *reinterpret_cast<const u32x4*>(xin + (size_t)(r0 + i * 16 + crow) * 128 + ccb * 8);

    // gather two fp8 rows (one 128B line each), fragment bytes contiguous per lane
    const int myrow = r0 + wv * 16 + m;
    int2 ids = ((const int2*)idmap)[myrow];
    const unsigned char* pa = xf8 + (size_t)ids.x * 128 + q * 32;
    const unsigned char* pb = xf8 + (size_t)ids.y * 128 + q * 32;
    u32x4 ga0 = *(const u32x4*)pa;
    u32x4 ga1 = *(const u32x4*)(pa + 16);
    u32x4 gb0 = *(const u32x4*)pb;
    u32x4 gb1 = *(const u32x4*)(pb + 16);

    bhalf8 afr[4];
    #pragma unroll
    for (int s = 0; s < 4; s++) {
        unsigned a0 = (s < 2) ? ga0[(s & 1) * 2]     : ga1[(s & 1) * 2];
        unsigned a1 = (s < 2) ? ga0[(s & 1) * 2 + 1] : ga1[(s & 1) * 2 + 1];
        unsigned b0 = (s < 2) ? gb0[(s & 1) * 2]     : gb1[(s & 1) * 2];
        unsigned b1 = (s < 2) ? gb0[(s & 1) * 2 + 1] : gb1[(s & 1) * 2 + 1];
        f32x2 s01 = __builtin_amdgcn_cvt_pk_f32_fp8((int)a0, false);
        f32x2 s23 = __builtin_amdgcn_cvt_pk_f32_fp8((int)a0, true);
        f32x2 s45 = __builtin_amdgcn_cvt_pk_f32_fp8((int)a1, false);
        f32x2 s67 = __builtin_amdgcn_cvt_pk_f32_fp8((int)a1, true);
        f32x2 t01 = __builtin_amdgcn_cvt_pk_f32_fp8((int)b0, false);
        f32x2 t23 = __builtin_amdgcn_cvt_pk_f32_fp8((int)b0, true);
        f32x2 t45 = __builtin_amdgcn_cvt_pk_f32_fp8((int)b1, false);
        f32x2 t67 = __builtin_amdgcn_cvt_pk_f32_fp8((int)b1, true);
        bhalf8 o;
        o[0] = (short)f2bf(s01[0] + t01[0]); o[1] = (short)f2bf(s01[1] + t01[1]);
        o[2] = (short)f2bf(s23[0] + t23[0]); o[3] = (short)f2bf(s23[1] + t23[1]);
        o[4] = (short)f2bf(s45[0] + t45[0]); o[5] = (short)f2bf(s45[1] + t45[1]);
        o[6] = (short)f2bf(s67[0] + t67[0]); o[7] = (short)f2bf(s67[1] + t67[1]);
        afr[s] = o;
    }

    f32x4 acc[8] = {};
    #pragma unroll
    for (int s = 0; s < 4; s++)
        #pragma unroll
        for (int t = 0; t < 8; t++)
            acc[t] = __builtin_amdgcn_mfma_f32_16x16x32_bf16(afr[s], wbn[(t * 4 + s) * 64 + lane], acc[t], 0, 0, 0);

    // stage g*scale (bf16) in C-layout
    const float scale = 0.25f * rez[0];
    #pragma unroll
    for (int t = 0; t < 8; t++) {
        float bb = bn[t * 16 + m];
        #pragma unroll
        for (int p = 0; p < 4; p++)
            gls[(wv * 16 + q * 4 + p) * 136 + t * 16 + m] = (short)f2bf(leaky(acc[t][p] + bb) * scale);
    }
    __syncthreads();

    // fused copy-out: xn = x_old + g*scale (x_old from prefetched regs), + heads on final pass
    #pragma unroll
    for (int i = 0; i < 4; i++) {
        int row = i * 16 + crow, cb = ccb;
        u32x4 gv = *(const u32x4*)&gls[row * 136 + cb * 8];
        u32x4 xv = xown[i];
        float xn[8];
        #pragma unroll
        for (int w = 0; w < 4; w++) {
            xn[2 * w]     = bflo(xv[w]) + bflo(gv[w]);
            xn[2 * w + 1] = bfhi(xv[w]) + bfhi(gv[w]);
        }
        if (!final_pass) {
            u32x4 ov;
            #pragma unroll
            for (int w = 0; w < 4; w++)
                ov[w] = (unsigned)f2bf(xn[2 * w]) | ((unsigned)f2bf(xn[2 * w + 1]) << 16);
            *reinterpret_cast<u32x4*>(reinterpret_cast<unsigned short*>(xout) + (size_t)(r0 + row) * 128 + cb * 8) = ov;
            u32x2 pf;
            pf[0] = pk4fp8(xn[0], xn[1], xn[2], xn[3]);
            pf[1] = pk4fp8(xn[4], xn[5], xn[6], xn[7]);
            *reinterpret_cast<u32x2*>(xf8out + (size_t)(r0 + row) * 128 + (cb & 3) * 32 + (cb >> 2) * 8) = pf;
        } else {
            float* op = reinterpret_cast<float*>(xout) + (size_t)(r0 + row) * 128 + cb * 8;
            f32x4 o0, o1;
            #pragma unroll
            for (int w = 0; w < 4; w++) { o0[w] = xn[w]; o1[w] = xn[4 + w]; }
            *reinterpret_cast<f32x4*>(op)     = o0;
            *reinterpret_cast<f32x4*>(op + 4) = o1;
            f32x4 w0 = *(const f32x4*)&Ww[cb * 8], w1 = *(const f32x4*)&Ww[cb * 8 + 4];
            f32x4 v0 = *(const f32x4*)&Wv[cb * 8], v1 = *(const f32x4*)&Wv[cb * 8 + 4];
            float ws = 0.0f, vs = 0.0f;
            #pragma unroll
            for (int w = 0; w < 4; w++) {
                ws += xn[w] * w0[w] + xn[4 + w] * w1[w];
                vs += xn[w] * v0[w] + xn[4 + w] * v1[w];
            }
            #pragma unroll
            for (int d = 1; d < 16; d <<= 1) {
                ws += __shfl_xor(ws, d, 64);
                vs += __shfl_xor(vs, d, 64);
            }
            if ((lane & 15) == 0) { wout[r0 + row] = ws; vout[r0 + row] = vs; }
        }
    }
}

extern "C" void kernel_launch(void* const* d_in, const int* in_sizes, int n_in,
                              void* d_out, int out_size, void* d_ws, size_t ws_size,
                              hipStream_t stream) {
    const float* feats = (const float*)d_in[0];
    const int*   idmap = (const int*)d_in[2];
    const float* smean = (const float*)d_in[3];
    const float* sstd  = (const float*)d_in[4];
    const float* Wemb  = (const float*)d_in[5];
    const float* bemb  = (const float*)d_in[6];
    const float* Wl    = (const float*)d_in[7];
    const float* bl    = (const float*)d_in[8];
    const float* Wn    = (const float*)d_in[9];
    const float* bn    = (const float*)d_in[10];
    const float* rez   = (const float*)d_in[11];
    const float* Ww    = (const float*)d_in[12];
    const float* Wv    = (const float*)d_in[13];

    char* ws = (char*)d_ws;
    unsigned short* wpack = (unsigned short*)ws;          // wembF @0, wlF @8192, wnF @24576 (shorts)
    float*          bembP = (float*)(ws + 81920);
    unsigned short* x1    = (unsigned short*)(ws + (1ull << 20));
    unsigned char*  x0f8  = (unsigned char*)(ws + (65ull << 20));
    unsigned char*  x1f8  = (unsigned char*)(ws + (97ull << 20));

    float* out = (float*)d_out;
    unsigned short* x0 = (unsigned short*)d_out;          // bf16 scratch in x_main region
    float* wout = out + (size_t)NROWS * 128;
    float* vout = wout + NROWS;

    setup_kernel<<<161, 256, 0, stream>>>(smean, sstd, Wemb, bemb, Wl, Wn, wpack, bembP);
    phase_a_kernel<<<NBLK, 256, 0, stream>>>(feats, wpack, bembP, wpack + 8192, bl, x0, x0f8);
    prop_kernel<unsigned short><<<NBLK, 256, 0, stream>>>(x0, x0f8, idmap, wpack + 24576, bn, rez, Ww, Wv,
                                                          x1, x1f8, nullptr, nullptr, 0);
    prop_kernel<float><<<NBLK, 256, 0, stream>>>(x1, x1f8, idmap, wpack + 24576, bn, rez, Ww, Wv,
                                                 out, nullptr, wout, vout, 1);
}